// Round 8
// baseline (125.359 us; speedup 1.0000x reference)
//
#include <hip/hip_runtime.h>
#include <hip/hip_bf16.h>

#define NB   64          // number of bins
#define NE   (NB + 1)    // number of edges
#define RC   32          // replica columns (one per bank)
#define ROWS (NB + 1)    // +1 trash row for invalid/masked-out elements

#define WAVES      4     // 256 threads
#define TILE_ELEMS 1024  // per block-tile (256 per wave)
#define WAVE_ELEMS 256   // per wave per tile: 64 lanes x 4 elems (16B/lane)
#define NBUF       3     // triple buffer -> prefetch depth 2

#define AS1CV const __attribute__((address_space(1))) void*
#define AS3V  __attribute__((address_space(3))) void*

// ---------------------------------------------------------------------------
// Branchless exact binning for affine (linspace) edges, verified bitwise per
// block. Guess is within 1 bin; one compare-adjust per direction. x == eN
// folds into the final min. Invalid (mask/range/NaN) -> row NB (trash).
// ---------------------------------------------------------------------------
#define BINV(x, mv, row)                                                     \
    {                                                                        \
        float t_ = ((x) - e0) * invstep;                                     \
        int g_ = (int)t_;                                                    \
        g_ = min(max(g_, 0), NB - 1);                                        \
        float gf_ = (float)g_;                                               \
        float lo_ = fmaf(gf_, step, e0);              /* == edges[g]   */    \
        float hi_ = fmaf(gf_ + 1.0f, step, e0);       /* == edges[g+1] */    \
        g_ += (hi_ <= (x)) ? 1 : 0;                                          \
        g_ -= (lo_ > (x)) ? 1 : 0;                                           \
        g_ = min(g_, NB - 1);                                                \
        bool valid_ = (mv) && ((x) >= e0) && ((x) <= eN);                    \
        (row) = valid_ ? g_ : NB;                                            \
    }

// Fallback: exact binning against arbitrary sorted edges (LDS pairs, loops).
__device__ __forceinline__ int bin_lds(float x, const float2* __restrict__ ep,
                                       float e0, float eN, float invstep) {
    if (!(x >= e0) || !(x <= eN)) return -1;
    if (x == eN) return NB - 1;
    int g = (int)((x - e0) * invstep);
    g = min(max(g, 0), NB - 1);
    float2 p = ep[g];
    while (p.x > x) { --g; p = ep[g]; }
    while (p.y <= x) { ++g; p = ep[g]; }
    return g;
}

#define WAITV(n) asm volatile("s_waitcnt vmcnt(" #n ")" ::: "memory")

// ---------------------------------------------------------------------------
// Hot loop: per-wave private pipeline, NO intra-loop barriers.
//   STAGE(buf,t):   3x global_load_lds_dwordx4 (obs/pred/mask) -> own slice
//   WAITV(6):       tile t's 3 loads done; t+1,t+2's 6 stay in flight
//   CONSUME:        ds_read_b128 x3 from own slice, bin, LDS atomics
// LDS hist layout [2][65][32]: bank = lane&31 always -> conflict-free.
// ---------------------------------------------------------------------------
template <bool AFFINE>
__device__ __forceinline__ void
run_tiles(const float* __restrict__ obs, const float* __restrict__ pred,
          const int* __restrict__ mask, size_t base, int NIT, int perBlock,
          int w, int lane, int tid,
          unsigned int (*s_stage)[WAVES][3][WAVE_ELEMS],
          unsigned int* __restrict__ hobs, unsigned int* __restrict__ hpred,
          const float2* __restrict__ s_epair,
          float e0, float eN, float step, float invstep)
{
#define STAGE(bi, t)                                                         \
    do {                                                                     \
        size_t eb_ = base + (size_t)(t) * TILE_ELEMS                         \
                     + (size_t)w * WAVE_ELEMS + (size_t)(lane << 2);         \
        unsigned long long l0_ = (unsigned long long)(void*)&s_stage[bi][w][0][0]; \
        unsigned long long l1_ = (unsigned long long)(void*)&s_stage[bi][w][1][0]; \
        unsigned long long l2_ = (unsigned long long)(void*)&s_stage[bi][w][2][0]; \
        asm volatile("" : "+v"(l0_), "+v"(l1_), "+v"(l2_));  /* launder */   \
        __builtin_amdgcn_global_load_lds((AS1CV)(obs  + eb_),                \
                                         (AS3V)(void*)l0_, 16, 0, 0);        \
        __builtin_amdgcn_global_load_lds((AS1CV)(pred + eb_),                \
                                         (AS3V)(void*)l1_, 16, 0, 0);        \
        __builtin_amdgcn_global_load_lds((AS1CV)(mask + eb_),                \
                                         (AS3V)(void*)l2_, 16, 0, 0);        \
    } while (0)

#define CONSUME(bi)                                                          \
    do {                                                                     \
        const float4* so_ = (const float4*)&s_stage[bi][w][0][0];            \
        const float4* sp_ = (const float4*)&s_stage[bi][w][1][0];            \
        const int4*   sm_ = (const int4*)&s_stage[bi][w][2][0];              \
        float4 o_ = so_[lane];                                               \
        float4 q_ = sp_[lane];                                               \
        int4   m_ = sm_[lane];                                               \
        int r0, r1, r2, r3, r4, r5, r6, r7;                                  \
        if (AFFINE) {                                                        \
            BINV(o_.x, m_.x, r0); BINV(q_.x, m_.x, r1);                      \
            BINV(o_.y, m_.y, r2); BINV(q_.y, m_.y, r3);                      \
            BINV(o_.z, m_.z, r4); BINV(q_.z, m_.z, r5);                      \
            BINV(o_.w, m_.w, r6); BINV(q_.w, m_.w, r7);                      \
        } else {                                                             \
            int tb_;                                                         \
            tb_ = bin_lds(o_.x, s_epair, e0, eN, invstep);                   \
            r0 = (m_.x && tb_ >= 0) ? tb_ : NB;                              \
            tb_ = bin_lds(q_.x, s_epair, e0, eN, invstep);                   \
            r1 = (m_.x && tb_ >= 0) ? tb_ : NB;                              \
            tb_ = bin_lds(o_.y, s_epair, e0, eN, invstep);                   \
            r2 = (m_.y && tb_ >= 0) ? tb_ : NB;                              \
            tb_ = bin_lds(q_.y, s_epair, e0, eN, invstep);                   \
            r3 = (m_.y && tb_ >= 0) ? tb_ : NB;                              \
            tb_ = bin_lds(o_.z, s_epair, e0, eN, invstep);                   \
            r4 = (m_.z && tb_ >= 0) ? tb_ : NB;                              \
            tb_ = bin_lds(q_.z, s_epair, e0, eN, invstep);                   \
            r5 = (m_.z && tb_ >= 0) ? tb_ : NB;                              \
            tb_ = bin_lds(o_.w, s_epair, e0, eN, invstep);                   \
            r6 = (m_.w && tb_ >= 0) ? tb_ : NB;                              \
            tb_ = bin_lds(q_.w, s_epair, e0, eN, invstep);                   \
            r7 = (m_.w && tb_ >= 0) ? tb_ : NB;                              \
        }                                                                    \
        atomicAdd(hobs  + (r0 << 5), 1u);                                    \
        atomicAdd(hpred + (r1 << 5), 1u);                                    \
        atomicAdd(hobs  + (r2 << 5), 1u);                                    \
        atomicAdd(hpred + (r3 << 5), 1u);                                    \
        atomicAdd(hobs  + (r4 << 5), 1u);                                    \
        atomicAdd(hpred + (r5 << 5), 1u);                                    \
        atomicAdd(hobs  + (r6 << 5), 1u);                                    \
        atomicAdd(hpred + (r7 << 5), 1u);                                    \
    } while (0)

    int t = 0;
    if (NIT > 0) STAGE(0, 0);
    if (NIT > 1) STAGE(1, 1);
    for (; t + 2 < NIT; ++t) {
        STAGE((t + 2) % NBUF, t + 2);
        WAITV(6);
        CONSUME(t % NBUF);
    }
    if (t < NIT) {
        if (t + 1 < NIT) { WAITV(3); CONSUME(t % NBUF); ++t; }
        WAITV(0);
        CONSUME(t % NBUF);
    }

    // generic remainder (none for the benchmark shape)
    for (int e = NIT * TILE_ELEMS + tid; e < perBlock; e += 256) {
        float o = obs[base + e];
        float q = pred[base + e];
        int   m = mask[base + e];
        int r0, r1;
        if (AFFINE) {
            BINV(o, m, r0);
            BINV(q, m, r1);
        } else {
            int tb_ = bin_lds(o, s_epair, e0, eN, invstep);
            r0 = (m && tb_ >= 0) ? tb_ : NB;
            tb_ = bin_lds(q, s_epair, e0, eN, invstep);
            r1 = (m && tb_ >= 0) ? tb_ : NB;
        }
        atomicAdd(hobs  + (r0 << 5), 1u);
        atomicAdd(hpred + (r1 << 5), 1u);
    }
#undef STAGE
#undef CONSUME
}

__global__ void __launch_bounds__(256, 4)
hist_kernel(const float* __restrict__ obs,
            const float* __restrict__ pred,
            const int*   __restrict__ mask,
            const float* __restrict__ edges,
            unsigned int* __restrict__ counts,   // [2][B][NB]
            int elemsPerBatch, int blocksPerBatch, int B)
{
    __shared__ unsigned int s_hist[2][ROWS][RC];
    __shared__ float2       s_epair[NB];
    __shared__ int          s_affine;
    __shared__ __align__(16) unsigned int s_stage[NBUF][WAVES][3][WAVE_ELEMS];

    const int tid = threadIdx.x;
    for (int i = tid; i < 2 * ROWS * RC; i += 256)
        (&s_hist[0][0][0])[i] = 0u;
    if (tid < NB) s_epair[tid] = make_float2(edges[tid], edges[tid + 1]);
    if (tid == 0) s_affine = 1;
    __syncthreads();

    const float e0 = edges[0];
    const float eN = edges[NB];
    const float step    = (eN - e0) / (float)NB;
    const float invstep = 1.0f / step;

    // verify register-reconstruction is bitwise-faithful to the edge array
    if (tid < NE) {
        float recon = fmaf((float)tid, step, e0);
        if (!(recon == edges[tid]) || !(step > 0.0f)) atomicAnd(&s_affine, 0);
    }
    __syncthreads();
    const bool affine = (s_affine != 0);

    const int b     = blockIdx.x / blocksPerBatch;
    const int chunk = blockIdx.x % blocksPerBatch;
    const int perBlock = elemsPerBatch / blocksPerBatch;
    const size_t base  = (size_t)b * (size_t)elemsPerBatch
                       + (size_t)chunk * (size_t)perBlock;
    const int NIT = perBlock / TILE_ELEMS;

    const int w    = tid >> 6;
    const int lane = tid & 63;
    const int c    = tid & (RC - 1);
    unsigned int* hobs  = &s_hist[0][0][0] + c;
    unsigned int* hpred = &s_hist[1][0][0] + c;

    if (affine)
        run_tiles<true >(obs, pred, mask, base, NIT, perBlock, w, lane, tid,
                         s_stage, hobs, hpred, s_epair, e0, eN, step, invstep);
    else
        run_tiles<false>(obs, pred, mask, base, NIT, perBlock, w, lane, tid,
                         s_stage, hobs, hpred, s_epair, e0, eN, step, invstep);

    __syncthreads();

    if (tid < NB) {
        unsigned int so = 0u, sp = 0u;
        #pragma unroll
        for (int r = 0; r < RC; ++r) {
            int col = (tid + r) & (RC - 1);      // rotated -> conflict-free
            so += s_hist[0][tid][col];
            sp += s_hist[1][tid][col];
        }
        if (so) atomicAdd(&counts[(size_t)b * NB + tid], so);
        if (sp) atomicAdd(&counts[(size_t)B * NB + (size_t)b * NB + tid], sp);
    }
}

// ---------------------------------------------------------------------------
// Kernel 2: finalize. One wave, lane t = bin t.
// out[0] = w2_loss, out[1 .. 1+B*NB) = p_obs, out[1+B*NB ..) = p_pred
// ---------------------------------------------------------------------------
__device__ __forceinline__ float wave_sum64(float v) {
    for (int o = 32; o > 0; o >>= 1) v += __shfl_xor(v, o, 64);
    return v;
}
__device__ __forceinline__ float wave_incl_scan64(float v, int lane) {
    for (int d = 1; d < 64; d <<= 1) {
        float u = __shfl_up(v, d, 64);
        if (lane >= d) v += u;
    }
    return v;
}

__global__ void __launch_bounds__(64)
finalize_kernel(const unsigned int* __restrict__ counts,
                const float* __restrict__ edges,
                const float* __restrict__ bweights,
                float* __restrict__ out, int B)
{
    const int t = threadIdx.x;    // 0..63 == bin index

    float midA = 0.5f * (edges[t] + edges[t + 1]);
    float width;
    if (t < NB - 1) {
        float midB = 0.5f * (edges[t + 1] + edges[t + 2]);
        width = midB - midA;
    } else {
        float midPrev = 0.5f * (edges[NB - 2] + edges[NB - 1]);
        width = midA - midPrev;
    }
    const float bw = bweights[t];

    float loss_acc = 0.0f;
    for (int b = 0; b < B; ++b) {
        float co = (float)counts[(size_t)b * NB + t];
        float cp = (float)counts[(size_t)B * NB + (size_t)b * NB + t];

        float to = wave_sum64(co);
        if (to == 0.0f) { co = 1.0f; to = 64.0f; }
        float tp = wave_sum64(cp);
        if (tp == 0.0f) { cp = 1.0f; tp = 64.0f; }

        float po = co / to;
        float pp = cp / tp;
        out[1 + (size_t)b * NB + t]                  = po;
        out[1 + (size_t)B * NB + (size_t)b * NB + t] = pp;

        float cdfo = wave_incl_scan64(po, t);
        float cdfp = wave_incl_scan64(pp, t);
        float d = cdfo - cdfp;
        float wd = d * d * width * bw;
        float s = wave_sum64(wd);
        if (t == 0) loss_acc += s;
    }
    if (t == 0) out[0] = loss_acc / (float)B;
}

// ---------------------------------------------------------------------------
extern "C" void kernel_launch(void* const* d_in, const int* in_sizes, int n_in,
                              void* d_out, int out_size, void* d_ws, size_t ws_size,
                              hipStream_t stream) {
    const float* obs      = (const float*)d_in[0];
    const float* pred     = (const float*)d_in[1];
    const int*   mask     = (const int*)d_in[2];
    const float* edges    = (const float*)d_in[3];
    const float* bweights = (const float*)d_in[4];
    float* out = (float*)d_out;

    const int nb = in_sizes[3] - 1;                 // 64
    const int B  = (out_size - 1) / (2 * nb);       // 32
    const int elemsPerBatch = in_sizes[0] / B;      // 1048576

    unsigned int* counts = (unsigned int*)d_ws;     // [2][B][nb] uint32
    const size_t countsBytes = (size_t)2 * B * nb * sizeof(unsigned int);

    hipMemsetAsync(d_ws, 0, countsBytes, stream);

    const int blocksPerBatch = 128;                 // 8192 elems / block
    dim3 grid(B * blocksPerBatch), block(256);
    hist_kernel<<<grid, block, 0, stream>>>(obs, pred, mask, edges, counts,
                                            elemsPerBatch, blocksPerBatch, B);

    finalize_kernel<<<1, 64, 0, stream>>>(counts, edges, bweights, out, B);
}